// Round 4
// baseline (113.636 us; speedup 1.0000x reference)
//
#include <hip/hip_runtime.h>

// KAN Convolutional Layer, fp32, MI355X. Round 4.
// x (16,32,64,64) f32 -> out (16, 256, 62, 62) f32.
//
// R3 was LDS-pipe bound (cycle model matched 53us within 4%). Fixes:
//  - weights folded to d_ws, read at wave-uniform addresses -> SGPR (s_load),
//    zero LDS weight traffic, zero weight VGPRs.
//  - features: silu SoA plane (b32) + basis as two float4 planes (b128),
//    contiguous stride-1 reads; 30 cyc/px vs 52.
//  - 5 output rows per wave amortize per-tap feature reads.

constexpr int Hh = 64, Ww = 64;
constexpr int Ho = 62, Wo = 62;
constexpr int L  = Ho * Wo;        // 3844
constexpr int NC = 8;              // n_convs
constexpr int RW  = 5;             // output rows per wave
constexpr int RPB = 20;            // 4 waves * 5 rows
constexpr int SR  = RPB + 2;       // staged input rows (max 22)
constexpr int NPX = SR * Ww;       // 1408
constexpr int NSTRIP = 4;          // ceil(62/20)

__global__ __launch_bounds__(128)
void fold_weights(const float* __restrict__ bw, const float* __restrict__ sw,
                  const float* __restrict__ scl, float* __restrict__ wf)
{
    // wf[k*72 + f*8 + n]: f=0 -> base_w, f=1..8 -> spline_w * scaler
    int i = threadIdx.x;                         // 0..127, need 0..71 per f-slot
    if (i < 72) {
        const int n = i & 7;
        const int k = i >> 3;
        const int m = n * 9 + k;
        const float sc = scl[m];
        wf[k * 72 + 0 * 8 + n] = bw[m];
#pragma unroll
        for (int f = 1; f < 9; f++)
            wf[k * 72 + f * 8 + n] = sw[m * 8 + (f - 1)] * sc;
    }
}

__global__ __launch_bounds__(256, 3)
void kan_conv_kernel(const float* __restrict__ x,
                     const float* __restrict__ wf,
                     float* __restrict__ out)
{
    __shared__ float  ssh[NPX];        //  5632 B  silu
    __shared__ float4 bsh0[NPX];       // 22528 B  basis f1..f4
    __shared__ float4 bsh1[NPX];       // 22528 B  basis f5..f8  (total 50688 B)

    const int strip = blockIdx.x & (NSTRIP - 1);
    const int bc    = blockIdx.x >> 2;           // b*32 + c
    const int s0    = strip * RPB;               // first output row of strip

    // ---- feature stage ----
    const int stage_rows = (s0 + SR <= Hh) ? SR : (Hh - s0);
    const int npx = stage_rows * Ww;
    const float* xp = x + (size_t)bc * (Hh * Ww) + (size_t)s0 * Ww;

    for (int p = threadIdx.x; p < npx; p += 256) {
        const float v  = xp[p];
        ssh[p] = v / (1.0f + __expf(-v));        // silu

        // uniform cubic B-spline closed form; knots (i-3)*0.4-1 -> u=(v+2.2)*2.5
        const float u  = (v + 2.2f) * 2.5f;
        const float fj = floorf(u);
        const float t  = u - fj;
        const int   j  = (int)fj - 3;            // basis slot of tap w0
        const float om = 1.0f - t;
        const float t2 = t * t;
        const float w3 = t * t2 * (1.0f / 6.0f);
        const float w0 = om * om * om * (1.0f / 6.0f);
        const float w1 = fmaf(t2, fmaf(t, 0.5f, -1.0f), 2.0f / 3.0f);
        const float w2 = 1.0f - w0 - w1 - w3;

        float b[8];
#pragma unroll
        for (int s = 0; s < 8; s++) {
            float r = 0.0f;
            r = (j == s    ) ? w0 : r;
            r = (j == s - 1) ? w1 : r;
            r = (j == s - 2) ? w2 : r;
            r = (j == s - 3) ? w3 : r;
            b[s] = r;
        }
        bsh0[p] = make_float4(b[0], b[1], b[2], b[3]);
        bsh1[p] = make_float4(b[4], b[5], b[6], b[7]);
    }
    __syncthreads();

    // ---- conv stage: wave -> 5 output rows, lane -> column ----
    const int wv = threadIdx.x >> 6;
    const int ln = threadIdx.x & 63;
    const int rbase = wv * RW;

    if (ln < Wo && s0 + rbase < Ho) {
        float acc[RW][NC];
#pragma unroll
        for (int r = 0; r < RW; r++)
#pragma unroll
            for (int n = 0; n < NC; n++) acc[r][n] = 0.0f;

#pragma unroll 1                      // rolled: body ~5KB, inside I-cache
        for (int k = 0; k < 9; k++) {
            const int kh = k / 3;
            const int kw = k - kh * 3;
            const float* __restrict__ w = wf + k * 72;   // wave-uniform -> SGPR

#pragma unroll
            for (int r = 0; r < RW; r++) {
                const int px = (rbase + r + kh) * Ww + ln + kw;
                const float  f0 = ssh[px];
                const float4 ba = bsh0[px];
                const float4 bb = bsh1[px];
#pragma unroll
                for (int n = 0; n < NC; n++) {
                    float a = acc[r][n];
                    a = fmaf(f0,   w[     n], a);
                    a = fmaf(ba.x, w[ 8 + n], a);
                    a = fmaf(ba.y, w[16 + n], a);
                    a = fmaf(ba.z, w[24 + n], a);
                    a = fmaf(ba.w, w[32 + n], a);
                    a = fmaf(bb.x, w[40 + n], a);
                    a = fmaf(bb.y, w[48 + n], a);
                    a = fmaf(bb.z, w[56 + n], a);
                    a = fmaf(bb.w, w[64 + n], a);
                    acc[r][n] = a;
                }
            }
        }

        // ---- stores: coalesced per (row, conv) plane ----
#pragma unroll
        for (int r = 0; r < RW; r++) {
            const int orow = s0 + rbase + r;
            if (orow < Ho) {
                const size_t ob = (size_t)bc * NC * L + (size_t)orow * Wo + ln;
#pragma unroll
                for (int n = 0; n < NC; n++) out[ob + (size_t)n * L] = acc[r][n];
            }
        }
    }
}

extern "C" void kernel_launch(void* const* d_in, const int* in_sizes, int n_in,
                              void* d_out, int out_size, void* d_ws, size_t ws_size,
                              hipStream_t stream) {
    const float* x   = (const float*)d_in[0];
    const float* bw  = (const float*)d_in[1];
    const float* sw  = (const float*)d_in[2];
    const float* scl = (const float*)d_in[3];
    float* wf  = (float*)d_ws;                 // 648 floats
    float* out = (float*)d_out;

    fold_weights<<<1, 128, 0, stream>>>(bw, sw, scl, wf);

    const int planes = in_sizes[0] / (Hh * Ww);   // 512
    dim3 grid(planes * NSTRIP);                   // 2048 blocks
    kan_conv_kernel<<<grid, 256, 0, stream>>>(x, wf, out);
}